// Round 8
// baseline (52.352 us; speedup 1.0000x reference)
//
#include <hip/hip_runtime.h>

// Problem geometry (fixed by the reference)
#define HH    2160
#define WW    3840
#define CROPC 3
#define NN    (HH - 2*CROPC)   // 2154 output rows
#define WFLAT (WW * 3)         // 11520 flat columns

constexpr int TY    = 32;           // output rows per block
constexpr int TXF   = 192;          // output flat cols per block; 11520/192 = 60
constexpr int SX    = TXF + 18;     // 210 flat halo cols (12 left, 6 right)
constexpr int NTH   = 256;
constexpr int TPR   = 8;            // phase-2 chunks per row (8 img cols each)
constexpr int XROWS = TY + 6;       // 38 input rows per tile

// De-interleaved LDS: 3 channel planes of [TY rows][PSTR cols] (+8 skew per plane).
constexpr int PSTR  = 76;           // mult of 4 (b128 rows); 76%32=12 spreads banks
constexpr int PLANE = TY * PSTR + 8; // 2440 dwords; total 29,280 B -> 5 blocks/CU

__device__ __forceinline__ float med3f(float a, float b, float c) {
    return fmaxf(fminf(a, b), fminf(fmaxf(a, b), c));
}
// median of 5: 4-element sort network + med3 merge (12 min/max)
__device__ __forceinline__ float med5f(float a, float b, float c, float d, float e) {
    float t;
    t = fminf(a, b); b = fmaxf(a, b); a = t;
    t = fminf(c, d); d = fmaxf(c, d); c = t;
    t = fminf(a, c); c = fmaxf(a, c); a = t;
    t = fminf(b, d); d = fmaxf(b, d); b = t;
    t = fminf(b, c); c = fmaxf(b, c); b = t;
    return fminf(c, fmaxf(b, e));
}

__global__ __launch_bounds__(NTH, 5) void fused_median(const float* __restrict__ img,
                                                       float* __restrict__ out) {
    __shared__ float v2s[3 * PLANE];   // 29,280 B

    const int tid = threadIdx.x;
    const int r0 = blockIdx.y * TY;
    const int f0 = blockIdx.x * TXF;

    // ---- Phase 1: vertical med5 + shift/med3, registers only (1 flat col/thread) ----
    if (tid < SX) {
        const int ch   = tid % 3;              // f0 mult of 3 -> channel = tid%3
        const int pcol = tid / 3;              // plane col 0..69 <-> img col f0/3-4+pcol
        const int cc   = min(max(f0 / 3 - 4 + pcol, 0), WW - 1);  // clamped img col
        const float* colp = img + (size_t)CROPC * WFLAT + (cc * 3 + ch);

        // Batch ALL 38 row loads, then pin the batch live (two asm groups):
        // all loads issue back-to-back, one vmcnt drain, no re-serialization.
        float xv[XROWS];
        #pragma unroll
        for (int i = 0; i < XROWS; ++i) {
            const int rr = min(max(r0 - 4 + i, 0), NN - 1);   // wave-uniform
            xv[i] = colp[(size_t)rr * WFLAT];
        }
        asm volatile("" ::
            "v"(xv[0]),  "v"(xv[1]),  "v"(xv[2]),  "v"(xv[3]),  "v"(xv[4]),
            "v"(xv[5]),  "v"(xv[6]),  "v"(xv[7]),  "v"(xv[8]),  "v"(xv[9]),
            "v"(xv[10]), "v"(xv[11]), "v"(xv[12]), "v"(xv[13]), "v"(xv[14]),
            "v"(xv[15]), "v"(xv[16]), "v"(xv[17]), "v"(xv[18]));
        asm volatile("" ::
            "v"(xv[19]), "v"(xv[20]), "v"(xv[21]), "v"(xv[22]), "v"(xv[23]),
            "v"(xv[24]), "v"(xv[25]), "v"(xv[26]), "v"(xv[27]), "v"(xv[28]),
            "v"(xv[29]), "v"(xv[30]), "v"(xv[31]), "v"(xv[32]), "v"(xv[33]),
            "v"(xv[34]), "v"(xv[35]), "v"(xv[36]), "v"(xv[37]));

        float vm2 = 0.f, vm1 = 0.f;
        #pragma unroll
        for (int i = 4; i < XROWS; ++i) {
            const float vc = med5f(xv[i-4], xv[i-3], xv[i-2], xv[i-1], xv[i]); // v[r0+i-6]
            if (i >= 6) {
                const int rz = r0 + i - 6;
                // v2[rz] = med3(v[rz-2], v[rz-1], v[rz]); shift1 edge algebra:
                //  rz==0 -> 0 ; rz==1 -> med3(0,v0,v1) ; rz==NN-1 -> v[NN-2]
                float a = vm2, b = vm1;
                if (rz == NN - 1) a = b;
                if (rz == 1)      a = 0.f;
                if (rz == 0)    { a = 0.f; b = 0.f; }
                v2s[ch * PLANE + (i - 6) * PSTR + pcol] = med3f(a, b, vc);
            }
            vm2 = vm1; vm1 = vc;
        }
    }
    __syncthreads();

    // ---- Phase 2: horizontal med5 + shift/med3; 32 rows x 8 chunks of 8 img cols ----
    const int lr    = tid >> 3;          // row 0..31
    const int kk    = tid & (TPR - 1);   // chunk 0..7
    const int r_out = r0 + lr;
    if (r_out >= NN) return;             // no barriers after this

    const int cbase = f0 / 3 + 8 * kk;   // first output img col (8 cols/thread)
    const bool edge = (cbase <= 1) || (cbase + 7 >= WW - 1);

    float o[24];
    #pragma unroll
    for (int c = 0; c < 3; ++c) {
        // plane cols 8kk .. 8kk+13 == img cols cbase-4 .. cbase+9 (clamped)
        const float* pb = &v2s[c * PLANE + lr * PSTR + 8 * kk];  // 32B aligned
        const float4 q0 = *(const float4*)(pb);
        const float4 q1 = *(const float4*)(pb + 4);
        const float4 q2 = *(const float4*)(pb + 8);
        const float2 q3 = *(const float2*)(pb + 12);
        const float ss[14] = {q0.x,q0.y,q0.z,q0.w, q1.x,q1.y,q1.z,q1.w,
                              q2.x,q2.y,q2.z,q2.w, q3.x,q3.y};
        float h[10];
        #pragma unroll
        for (int m = 0; m < 10; ++m)
            h[m] = med5f(ss[m], ss[m+1], ss[m+2], ss[m+3], ss[m+4]); // h1[cbase-2+m]
        if (!edge) {
            #pragma unroll
            for (int n = 0; n < 8; ++n)
                o[3*n + c] = med3f(h[n], h[n+1], h[n+2]);
        } else {
            #pragma unroll
            for (int n = 0; n < 8; ++n) {
                const int ci = cbase + n;
                float A = h[n], B = h[n+1];
                if (ci == WW - 1) A = B;
                if (ci == 1)      A = 0.f;
                if (ci == 0)    { A = 0.f; B = 0.f; }
                o[3*n + c] = med3f(A, B, h[n+2]);
            }
        }
    }

    // 6 aligned float4 stores, 96 B contiguous per thread
    float4* op = (float4*)(out + (size_t)r_out * WFLAT + f0 + 24 * kk);
    #pragma unroll
    for (int q = 0; q < 6; ++q)
        op[q] = make_float4(o[4*q], o[4*q+1], o[4*q+2], o[4*q+3]);
}

extern "C" void kernel_launch(void* const* d_in, const int* in_sizes, int n_in,
                              void* d_out, int out_size, void* d_ws, size_t ws_size,
                              hipStream_t stream) {
    const float* img = (const float*)d_in[0];   // (2160, 3840, 3) fp32
    // d_in[1] = mask (unused by reference), d_in[2] = vertical_size (== 5)
    float* out = (float*)d_out;                 // (2154, 3840, 3) fp32
    dim3 grid(WFLAT / TXF, (NN + TY - 1) / TY); // 60 x 68
    fused_median<<<grid, NTH, 0, stream>>>(img, out);
}

// Round 9
// 48.646 us; speedup vs baseline: 1.0762x; 1.0762x over previous
//
#include <hip/hip_runtime.h>

// Problem geometry (fixed by the reference)
#define HH    2160
#define WW    3840
#define CROPC 3
#define NN    (HH - 2*CROPC)   // 2154 output rows
#define WFLAT (WW * 3)         // 11520 flat columns

constexpr int TY    = 16;           // output rows per block (occupancy winner, R4)
constexpr int TXF   = 192;          // output flat cols per block; 11520/192 = 60
constexpr int SX    = TXF + 18;     // 210 flat halo cols (12 left, 6 right)
constexpr int NTH   = 256;
constexpr int TPR   = 16;           // phase-2 threads per row
constexpr int XROWS = TY + 6;       // 22 input rows per tile

// De-interleaved LDS: 3 channel planes of [TY rows][PSTR cols] (+8 skew per plane).
constexpr int PSTR  = 76;           // mult of 4 (b128-aligned rows); 76%32=12 spreads banks
constexpr int PLANE = TY * PSTR + 8; // 1224 dwords; total 14,688 B -> 8 blocks/CU

// Single-instruction 3-input median (hipcc does not reliably pattern-match this)
__device__ __forceinline__ float vmed3(float a, float b, float c) {
    float r;
    asm("v_med3_f32 %0, %1, %2, %3" : "=v"(r) : "v"(a), "v"(b), "v"(c));
    return r;
}

__global__ __launch_bounds__(NTH, 8) void fused_median(const float* __restrict__ img,
                                                       float* __restrict__ out) {
    __shared__ float v2s[3 * PLANE];   // 14,688 B

    const int tid = threadIdx.x;
    const int r0 = blockIdx.y * TY;
    const int f0 = blockIdx.x * TXF;

    // ---- Phase 1: vertical med5 + shift/med3, registers only (1 flat col/thread) ----
    if (tid < SX) {
        const int ch   = tid % 3;              // f0 mult of 3 -> channel = tid%3
        const int pcol = tid / 3;              // plane col 0..69 <-> img col f0/3-4+pcol
        const int cc   = min(max(f0 / 3 - 4 + pcol, 0), WW - 1);  // clamped img col
        const float* colp = img + (size_t)CROPC * WFLAT + (cc * 3 + ch);

        // Batch ALL 22 row loads (proven to pin the batch live: R7, VGPR=24)
        float xv[XROWS];
        #pragma unroll
        for (int i = 0; i < XROWS; ++i) {
            const int rr = min(max(r0 - 4 + i, 0), NN - 1);   // wave-uniform
            xv[i] = colp[(size_t)rr * WFLAT];
        }
        asm volatile("" ::
            "v"(xv[0]),  "v"(xv[1]),  "v"(xv[2]),  "v"(xv[3]),  "v"(xv[4]),
            "v"(xv[5]),  "v"(xv[6]),  "v"(xv[7]),  "v"(xv[8]),  "v"(xv[9]),
            "v"(xv[10]), "v"(xv[11]), "v"(xv[12]), "v"(xv[13]), "v"(xv[14]),
            "v"(xv[15]), "v"(xv[16]), "v"(xv[17]), "v"(xv[18]), "v"(xv[19]),
            "v"(xv[20]), "v"(xv[21]));

        // Sliding med5 via shared pair-sorts:
        //   med5(w0..w4) = med3(w4, max(lo(w0,w1), lo(w2,w3)), min(hi(w0,w1), hi(w2,w3)))
        // (for any pairing of the first 4, {max-of-los, min-of-his} = {2nd,3rd} smallest).
        // Window s (s=0..17) -> v[r0+s-2] uses pairs s and s+2, e = xv[s+4].
        float lo0 = fminf(xv[0], xv[1]), hi0 = fmaxf(xv[0], xv[1]);   // pair 0
        float lo1 = fminf(xv[1], xv[2]), hi1 = fmaxf(xv[1], xv[2]);   // pair 1
        float vm2 = 0.f, vm1 = 0.f;
        #pragma unroll
        for (int s = 0; s < 18; ++s) {
            const float lo2 = fminf(xv[s+2], xv[s+3]);   // pair s+2
            const float hi2 = fmaxf(xv[s+2], xv[s+3]);
            const float vc  = vmed3(xv[s+4], fmaxf(lo0, lo2), fminf(hi0, hi2)); // v[r0+s-2]
            if (s >= 2) {
                const int rz = r0 + s - 2;
                // v2[rz] = med3(v[rz-2], v[rz-1], v[rz]); shift1 edge algebra:
                //  rz==0 -> 0 ; rz==1 -> med3(0,v0,v1) ; rz==NN-1 -> v[NN-2]
                float a = vm2, b = vm1;
                if (rz == NN - 1) a = b;
                if (rz == 1)      a = 0.f;
                if (rz == 0)    { a = 0.f; b = 0.f; }
                v2s[ch * PLANE + (s - 2) * PSTR + pcol] = vmed3(a, b, vc);
            }
            lo0 = lo1; hi0 = hi1; lo1 = lo2; hi1 = hi2;
            vm2 = vm1; vm1 = vc;
        }
    }
    __syncthreads();

    // ---- Phase 2: horizontal med5 + shift/med3; 16 rows x 16 chunks of 4 img cols ----
    const int lr    = tid >> 4;          // row 0..15
    const int kk    = tid & (TPR - 1);   // chunk 0..15
    const int r_out = r0 + lr;
    if (r_out >= NN) return;             // no barriers after this

    const int cbase = f0 / 3 + 4 * kk;   // first output img col (4 cols/thread)
    const bool edge = (cbase <= 1) || (cbase + 3 >= WW - 1);

    float o[12];
    #pragma unroll
    for (int c = 0; c < 3; ++c) {
        // plane cols 4kk .. 4kk+9 == img cols cbase-4 .. cbase+5 (clamped)
        const float* pb = &v2s[c * PLANE + lr * PSTR + 4 * kk];  // 16B aligned
        const float4 q0 = *(const float4*)(pb);
        const float4 q1 = *(const float4*)(pb + 4);
        const float2 q2 = *(const float2*)(pb + 8);
        const float ss[10] = {q0.x,q0.y,q0.z,q0.w, q1.x,q1.y,q1.z,q1.w,
                              q2.x,q2.y};
        // shared pair-sorts across the 6 sliding windows (pairs 0..7)
        float plo[8], phi[8];
        #pragma unroll
        for (int i = 0; i < 8; ++i) {
            plo[i] = fminf(ss[i], ss[i+1]);
            phi[i] = fmaxf(ss[i], ss[i+1]);
        }
        float h[6];
        #pragma unroll
        for (int m = 0; m < 6; ++m)      // h1[cbase-2+m]
            h[m] = vmed3(ss[m+4], fmaxf(plo[m], plo[m+2]), fminf(phi[m], phi[m+2]));
        if (!edge) {
            #pragma unroll
            for (int n = 0; n < 4; ++n)
                o[3*n + c] = vmed3(h[n], h[n+1], h[n+2]);
        } else {
            #pragma unroll
            for (int n = 0; n < 4; ++n) {
                const int ci = cbase + n;
                float A = h[n], B = h[n+1];
                if (ci == WW - 1) A = B;
                if (ci == 1)      A = 0.f;
                if (ci == 0)    { A = 0.f; B = 0.f; }
                o[3*n + c] = vmed3(A, B, h[n+2]);
            }
        }
    }

    // 3 aligned float4 stores (f0 + 12kk mult of 4)
    float4* op = (float4*)(out + (size_t)r_out * WFLAT + f0 + 12 * kk);
    op[0] = make_float4(o[0], o[1], o[2],  o[3]);
    op[1] = make_float4(o[4], o[5], o[6],  o[7]);
    op[2] = make_float4(o[8], o[9], o[10], o[11]);
}

extern "C" void kernel_launch(void* const* d_in, const int* in_sizes, int n_in,
                              void* d_out, int out_size, void* d_ws, size_t ws_size,
                              hipStream_t stream) {
    const float* img = (const float*)d_in[0];   // (2160, 3840, 3) fp32
    // d_in[1] = mask (unused by reference), d_in[2] = vertical_size (== 5)
    float* out = (float*)d_out;                 // (2154, 3840, 3) fp32
    dim3 grid(WFLAT / TXF, (NN + TY - 1) / TY); // 60 x 135
    fused_median<<<grid, NTH, 0, stream>>>(img, out);
}